// Round 10
// baseline (230.104 us; speedup 1.0000x reference)
//
#include <hip/hip_runtime.h>
#include <hip/hip_bf16.h>

// Problem constants
#define BB 8
#define NN 4096
#define EE 65536            // edges per graph
#define BE (BB*EE)          // 524288 total edges
#define BN (BB*NN)          // 32768 total nodes
#define INF 128
#define HID 512
#define CC 2
#define OUTC 10
#define ELLCAP 64           // max in-degree capacity (Binomial mean 16, P(>=64)<1e-13)

typedef __bf16 bf16x8_t __attribute__((ext_vector_type(8)));
typedef float  f32x4_t  __attribute__((ext_vector_type(4)));

__device__ __forceinline__ ushort f2bf(float f) {
  union { float f; unsigned u; } v; v.f = f;
  unsigned r = v.u + 0x7FFFu + ((v.u >> 16) & 1u);   // RNE
  return (ushort)(r >> 16);
}
__device__ __forceinline__ float bf2f(ushort s) {
  union { unsigned u; float f; } v; v.u = ((unsigned)s) << 16;
  return v.f;
}

// ---------------------------------------------------------------------------
// Kernel FRONT (fused): three independent prep stages in one launch.
// XCD-locality: for cast_x and ell_build, blk&7 selects the GRAPH.
// ---------------------------------------------------------------------------
__global__ __launch_bounds__(256) void front(
    const int* __restrict__ src, const int* __restrict__ dst,
    const float* __restrict__ ew, const float* __restrict__ x,
    const float* __restrict__ Wrel, const float* __restrict__ Wroot,
    int* __restrict__ deg, int2* __restrict__ ell,
    ushort* __restrict__ Ab, ushort* __restrict__ Bb) {
  int blk = blockIdx.x;
  int tid = threadIdx.x;
  if (blk < 4096) {
    int g = (blk & 7) * 131072 + (blk >> 3) * 256 + tid;   // 0..1048575
    float4 v = *(const float4*)&x[(size_t)g * 4];
    int m = g >> 5;
    int kin = (g & 31) * 4;
    ushort4 o;
    o.x = f2bf(v.x); o.y = f2bf(v.y); o.z = f2bf(v.z); o.w = f2bf(v.w);
    *(ushort4*)&Ab[(size_t)m * 256 + 128 + kin] = o;
  } else if (blk < 6144) {
    int bl = blk - 4096;                       // 0..2047 (2048 ≡ 0 mod 8)
    int e = (bl & 7) * EE + (bl >> 3) * 256 + tid;   // 0..524287
    int d = dst[e];
    int p = atomicAdd(&deg[d], 1);
    if (p < ELLCAP) {
      int2 v; v.x = src[e]; v.y = __float_as_int(ew[e]);
      ell[(size_t)d * ELLCAP + p] = v;
    }
  } else {
    int g = (blk - 6144) * 256 + tid;          // 0..131071
    int n = g & 511, k = g >> 9;
    float w = (k < 128) ? Wrel[k * 512 + n] : Wroot[(k - 128) * 512 + n];
    Bb[n * 256 + k] = f2bf(w);
  }
}

// ---------------------------------------------------------------------------
// Kernel A5: gather  A[n, 0:128] = bf16( sum_j w_j * xbf16[src_j,:] )
// One node per WAVE; 4 edges/iter, uint4 feature slices. blk&7 = graph.
// ---------------------------------------------------------------------------
__global__ __launch_bounds__(256) void gather_ell(
    const int* __restrict__ deg, const int2* __restrict__ ell,
    ushort* __restrict__ Ab) {
  int blk = blockIdx.x;
  int n = (blk & 7) * NN + (blk >> 3) * 4 + (threadIdx.x >> 6);
  int lane = threadIdx.x & 63;
  int l4 = lane >> 4;          // edge slot 0..3
  int fl = lane & 15;          // feature slice
  int d = deg[n]; if (d > ELLCAP) d = ELLCAP;
  const int2* ep = ell + (size_t)n * ELLCAP;

  float a[8] = {0, 0, 0, 0, 0, 0, 0, 0};
  int j = 0;
  for (; j + 7 < d; j += 8) {
    int2 v0 = ep[j + l4];
    int2 v1 = ep[j + 4 + l4];
    uint4 u0 = *(const uint4*)&Ab[(size_t)v0.x * 256 + 128 + fl * 8];
    uint4 u1 = *(const uint4*)&Ab[(size_t)v1.x * 256 + 128 + fl * 8];
    float w0 = __int_as_float(v0.y);
    float w1 = __int_as_float(v1.y);
    const ushort* s0 = (const ushort*)&u0;
    const ushort* s1 = (const ushort*)&u1;
#pragma unroll
    for (int q = 0; q < 8; ++q)
      a[q] += w0 * bf2f(s0[q]) + w1 * bf2f(s1[q]);
  }
  for (; j + 3 < d; j += 4) {
    int2 v0 = ep[j + l4];
    uint4 u0 = *(const uint4*)&Ab[(size_t)v0.x * 256 + 128 + fl * 8];
    float w0 = __int_as_float(v0.y);
    const ushort* s0 = (const ushort*)&u0;
#pragma unroll
    for (int q = 0; q < 8; ++q)
      a[q] += w0 * bf2f(s0[q]);
  }
  {
    int idx = j + l4;
    if (idx < d) {
      int2 v0 = ep[idx];
      uint4 u0 = *(const uint4*)&Ab[(size_t)v0.x * 256 + 128 + fl * 8];
      float w0 = __int_as_float(v0.y);
      const ushort* s0 = (const ushort*)&u0;
#pragma unroll
      for (int q = 0; q < 8; ++q)
        a[q] += w0 * bf2f(s0[q]);
    }
  }
#pragma unroll
  for (int q = 0; q < 8; ++q) {
    a[q] += __shfl_xor(a[q], 16, 64);
    a[q] += __shfl_xor(a[q], 32, 64);
  }
  if (l4 == 0) {
    ushort o[8];
#pragma unroll
    for (int q = 0; q < 8; ++q) o[q] = f2bf(a[q]);
    *(uint4*)&Ab[(size_t)n * 256 + fl * 8] = *(const uint4*)o;
  }
}

// ---------------------------------------------------------------------------
// Kernel CP3: gemm_pool, single-GEMM register-h version (R9 post-mortem fix).
// 512 blocks (blk&7 = graph = XCD), 64-row strip per block.
// Pass 1: MFMA over 8 col-chunks; per chunk, accumulate logit partials AND
//         pack h into registers (uint hpk[8][4][2], 2 bf16/uint, all indices
//         compile-time). Softmax s per row -> ssv + global s/slog.
// Pass 2: pure-VALU register sweep: o = s^T h from hpk (no B re-stage, no
//         second MFMA pass). Barriers 17 -> ~10.
// LDS ~75 KB -> 2 blocks/CU.
// ---------------------------------------------------------------------------
__global__ __launch_bounds__(256) void gemm_pool(
    const ushort* __restrict__ Ab, const ushort* __restrict__ Bb,
    const float* __restrict__ brel, const float* __restrict__ Wp,
    const float* __restrict__ bp, float* __restrict__ s,
    float* __restrict__ slog, float* __restrict__ outpart,
    float* __restrict__ ssacc) {
  __shared__ ushort As[64 * 256];   // 32 KB
  __shared__ ushort Bs[64 * 256];   // 32 KB
  __shared__ float wpS[1024];       // 4 KB   Wp staged
  __shared__ float brS[512];        // 2 KB   brel staged
  __shared__ float2 ssv[64];        // 512 B  per-row (s0,s1)
  __shared__ float ssrw[16][3];     // 192 B
  __shared__ float oacc[1024];      // 4 KB   o0 [0,512) / o1 [512,1024)
  int tid = threadIdx.x;
  int blk = blockIdx.x;
  int b = blk & 7;                  // graph = XCD
  int chunk = blk >> 3;             // 0..63
  int m0 = b * NN + chunk * 64;
  int obik = b * 64 + chunk;

  // stage As once (coalesced, XOR-swizzled) + wp/brel + zero oacc
#pragma unroll
  for (int i = 0; i < 8; ++i) {
    int g = tid + i * 256;
    int r = g >> 5, c = g & 31;
    int cs = c ^ (r & 31);
    *(uint4*)&As[(r * 32 + cs) * 8] = *(const uint4*)&Ab[(size_t)(m0 + r) * 256 + c * 8];
  }
  *(float4*)&wpS[tid * 4] = *(const float4*)&Wp[tid * 4];
  if (tid < 128) *(float4*)&brS[tid * 4] = *(const float4*)&brel[tid * 4];
  *(float4*)&oacc[tid * 4] = (float4){0.f, 0.f, 0.f, 0.f};

  int wave = tid >> 6, lane = tid & 63;
  int wm = wave * 16;
  int l16 = lane & 15, quad = lane >> 4;
  int arow = wm + l16;
  float bp0 = bp[0], bp1 = bp[1];

  float la0[4] = {0, 0, 0, 0}, la1[4] = {0, 0, 0, 0};
  uint hpk[8][4][2];   // packed bf16 h: [chunk][ct][rpair], static indices only

  // ---------------- pass 1: GEMM + logit partials + h pack ----------------
  for (int cc = 0; cc < 8; ++cc) {
    int n0 = cc * 64;
#pragma unroll
    for (int i = 0; i < 8; ++i) {
      int g = tid + i * 256;
      int r = g >> 5, c = g & 31;
      int cs = c ^ (r & 31);
      *(uint4*)&Bs[(r * 32 + cs) * 8] = *(const uint4*)&Bb[(size_t)(n0 + r) * 256 + c * 8];
    }
    __syncthreads();

    f32x4_t acc[4];
#pragma unroll
    for (int ct = 0; ct < 4; ++ct) acc[ct] = (f32x4_t){0.f, 0.f, 0.f, 0.f};
#pragma unroll
    for (int kc = 0; kc < 8; ++kc) {
      int cl = kc * 4 + quad;
      bf16x8_t af = *(const bf16x8_t*)&As[(arow * 32 + (cl ^ (arow & 31))) * 8];
#pragma unroll
      for (int ct = 0; ct < 4; ++ct) {
        int brow = ct * 16 + l16;
        bf16x8_t bf = *(const bf16x8_t*)&Bs[(brow * 32 + (cl ^ (brow & 31))) * 8];
        acc[ct] = __builtin_amdgcn_mfma_f32_16x16x32_bf16(af, bf, acc[ct], 0, 0, 0);
      }
    }
#pragma unroll
    for (int ct = 0; ct < 4; ++ct) {
      int col = cc * 64 + ct * 16 + l16;
      float bias = brS[col];
      float w0 = wpS[col * 2], w1 = wpS[col * 2 + 1];
      float h0 = fmaxf(acc[ct][0] + bias, 0.f);
      float h1 = fmaxf(acc[ct][1] + bias, 0.f);
      float h2 = fmaxf(acc[ct][2] + bias, 0.f);
      float h3 = fmaxf(acc[ct][3] + bias, 0.f);
      la0[0] += h0 * w0; la1[0] += h0 * w1;
      la0[1] += h1 * w0; la1[1] += h1 * w1;
      la0[2] += h2 * w0; la1[2] += h2 * w1;
      la0[3] += h3 * w0; la1[3] += h3 * w1;
      hpk[cc][ct][0] = (uint)f2bf(h0) | ((uint)f2bf(h1) << 16);
      hpk[cc][ct][1] = (uint)f2bf(h2) | ((uint)f2bf(h3) << 16);
    }
    __syncthreads();   // Bs consumed
  }

  // reduce logits over the 16 l16 lanes (cols) within each quad group
#pragma unroll
  for (int r = 0; r < 4; ++r) {
#pragma unroll
    for (int m = 1; m < 16; m <<= 1) {
      la0[r] += __shfl_xor(la0[r], m, 64);
      la1[r] += __shfl_xor(la1[r], m, 64);
    }
  }
  if (l16 == 0) {
    float sa = 0.f, sb = 0.f, sc2 = 0.f;
#pragma unroll
    for (int r = 0; r < 4; ++r) {
      int row = wm + quad * 4 + r;
      int n = m0 + row;
      float l0 = la0[r] + bp0, l1 = la1[r] + bp1;
      slog[n * 2] = l0;
      slog[n * 2 + 1] = l1;
      float mm = fmaxf(l0, l1);
      float e0 = expf(l0 - mm), e1 = expf(l1 - mm);
      float inv = 1.f / (e0 + e1);
      float s0 = e0 * inv, s1 = e1 * inv;
      *(float2*)&s[n * 2] = make_float2(s0, s1);
      ssv[row] = make_float2(s0, s1);
      sa += s0 * s0; sb += s0 * s1; sc2 += s1 * s1;
    }
    int idx = wave * 4 + quad;
    ssrw[idx][0] = sa; ssrw[idx][1] = sb; ssrw[idx][2] = sc2;
  }
  __syncthreads();   // ssv visible to all

  // ---------------- pass 2: register sweep o = s^T h ----------------
  {
    float2 sv0 = ssv[wm + quad * 4 + 0];
    float2 sv1 = ssv[wm + quad * 4 + 1];
    float2 sv2 = ssv[wm + quad * 4 + 2];
    float2 sv3 = ssv[wm + quad * 4 + 3];
#pragma unroll
    for (int cc = 0; cc < 8; ++cc) {
#pragma unroll
      for (int ct = 0; ct < 4; ++ct) {
        int col = cc * 64 + ct * 16 + l16;
        uint p0 = hpk[cc][ct][0];
        uint p1 = hpk[cc][ct][1];
        float h0 = bf2f((ushort)(p0 & 0xFFFFu));
        float h1 = bf2f((ushort)(p0 >> 16));
        float h2 = bf2f((ushort)(p1 & 0xFFFFu));
        float h3 = bf2f((ushort)(p1 >> 16));
        float v0 = sv0.x * h0 + sv1.x * h1 + sv2.x * h2 + sv3.x * h3;
        float v1 = sv0.y * h0 + sv1.y * h1 + sv2.y * h2 + sv3.y * h3;
        v0 += __shfl_xor(v0, 16, 64); v0 += __shfl_xor(v0, 32, 64);
        v1 += __shfl_xor(v1, 16, 64); v1 += __shfl_xor(v1, 32, 64);
        if (lane < 16) {
          atomicAdd(&oacc[col], v0);
          atomicAdd(&oacc[512 + col], v1);
        }
      }
    }
  }
  __syncthreads();

  // epilogue: outpart + ssacc
#pragma unroll
  for (int q = 0; q < 4; ++q) {
    int idx = tid + q * 256;
    outpart[(size_t)obik * 1024 + idx] = oacc[idx];
  }
  if (tid < 3) {
    float v = 0.f;
#pragma unroll
    for (int i = 0; i < 16; ++i) v += ssrw[i][tid];
    atomicAdd(&ssacc[b * 4 + tid], v);
  }
}

// ---------------------------------------------------------------------------
// Kernel E: out_adj_raw[b,i,j] = sum_e w_e * s[src,i] * s[dst,j]
// + mincut_den[b]. XCD-locality: blk&7 = graph.
// ---------------------------------------------------------------------------
__global__ __launch_bounds__(256) void edge_pass2(
    const int* __restrict__ src, const int* __restrict__ dst,
    const float* __restrict__ ew, const float* __restrict__ s,
    float* __restrict__ oadj, float* __restrict__ mden) {
  int b = blockIdx.x & 7;
  int sub = blockIdx.x >> 3;
  int base = b * EE + sub * 1024;
  float p00 = 0, p01 = 0, p10 = 0, p11 = 0, md = 0;
  for (int i = threadIdx.x; i < 1024; i += 256) {
    int e = base + i;
    int r = src[e], c = dst[e];
    float w = ew[e];
    float s0r = s[r * 2], s1r = s[r * 2 + 1];
    float s0c = s[c * 2], s1c = s[c * 2 + 1];
    p00 += w * s0r * s0c; p01 += w * s0r * s1c;
    p10 += w * s1r * s0c; p11 += w * s1r * s1c;
    md  += w * (s0r * s0r + s1r * s1r);
  }
#pragma unroll
  for (int off = 32; off; off >>= 1) {
    p00 += __shfl_down(p00, off, 64);
    p01 += __shfl_down(p01, off, 64);
    p10 += __shfl_down(p10, off, 64);
    p11 += __shfl_down(p11, off, 64);
    md  += __shfl_down(md,  off, 64);
  }
  __shared__ float red[4][5];
  int wave = threadIdx.x >> 6, lane = threadIdx.x & 63;
  if (lane == 0) {
    red[wave][0] = p00; red[wave][1] = p01;
    red[wave][2] = p10; red[wave][3] = p11;
    red[wave][4] = md;
  }
  __syncthreads();
  if (threadIdx.x < 4) {
    float v = red[0][threadIdx.x] + red[1][threadIdx.x] +
              red[2][threadIdx.x] + red[3][threadIdx.x];
    atomicAdd(&oadj[b * 4 + threadIdx.x], v);
  } else if (threadIdx.x == 4) {
    float v = red[0][4] + red[1][4] + red[2][4] + red[3][4];
    atomicAdd(&mden[b], v);
  }
}

// ---------------------------------------------------------------------------
// Kernel G1: per-graph scalars + u,v build. 64 blocks = b(8) x fc(8).
// ---------------------------------------------------------------------------
__global__ __launch_bounds__(256) void finalize_a(
    const float* __restrict__ outpart, const float* __restrict__ oadj,
    const float* __restrict__ ssacc, const float* __restrict__ mden,
    float* __restrict__ uv, float* __restrict__ lossp,
    float* __restrict__ dout) {
  __shared__ float sc[2];
  __shared__ float r0[256], r1[256];
  int b = blockIdx.x >> 3, fc = blockIdx.x & 7;
  int t = threadIdx.x;
  if (t == 0) {
    float r00 = oadj[b * 4 + 0], r01 = oadj[b * 4 + 1];
    float r10 = oadj[b * 4 + 2], r11 = oadj[b * 4 + 3];
    float d20 = sqrtf(r01) + 1e-15f;
    float d21 = sqrtf(r10) + 1e-15f;
    float oa01 = r01 / (d20 * d21);
    float oa10 = r10 / (d21 * d20);
    sc[0] = oa01; sc[1] = oa10;
    if (fc == 0) {
      lossp[b * 2 + 0] = -((r00 + r11) / mden[b]) / (float)BB;
      float a = ssacc[b * 4 + 0], bb = ssacc[b * 4 + 1], c = ssacc[b * 4 + 2];
      float nrm = sqrtf(a * a + 2.f * bb * bb + c * c);
      float q = 0.70710678118654752f;
      float da = a / nrm - q, db = bb / nrm, dc = c / nrm - q;
      lossp[b * 2 + 1] = sqrtf(da * da + 2.f * db * db + dc * dc) / (float)BB;
      dout[65618 + b * 4 + 0] = 0.f;
      dout[65618 + b * 4 + 1] = oa01;
      dout[65618 + b * 4 + 2] = oa10;
      dout[65618 + b * 4 + 3] = 0.f;
    }
  }
  __syncthreads();
  int f = fc * 64 + (t & 63);
  int ic = t >> 6;                         // 0..3 -> 16 i's each
  float o0s = 0.f, o1s = 0.f;
  for (int i = ic * 16; i < ic * 16 + 16; ++i) {
    o0s += outpart[(size_t)(b * 64 + i) * 1024 + f];
    o1s += outpart[(size_t)(b * 64 + i) * 1024 + 512 + f];
  }
  r0[ic * 64 + (t & 63)] = o0s;
  r1[ic * 64 + (t & 63)] = o1s;
  __syncthreads();
  if (ic == 0) {
    int fl = t & 63;
    float a0 = r0[fl] + r0[64 + fl] + r0[128 + fl] + r0[192 + fl];
    float a1 = r1[fl] + r1[64 + fl] + r1[128 + fl] + r1[192 + fl];
    uv[b * HID + f] = sc[1] * a1 + sc[0] * a0;   // u = oa10*o1 + oa01*o0
    uv[BB * HID + b * HID + f] = a0 + a1;        // v
  }
}

// ---------------------------------------------------------------------------
// Kernel G2: conv3 split-K partials. Grid 128 = kc(16) x fc(8).
// ---------------------------------------------------------------------------
__global__ __launch_bounds__(256) void conv3_part(
    const float* __restrict__ uv, const float* __restrict__ Wrel3,
    const float* __restrict__ Wroot3, float* __restrict__ xmacc) {
  __shared__ float us[8][32], vs[8][32];
  __shared__ float red[4][64][8];
  int blk = blockIdx.x;
  int fc = blk & 7, kc = blk >> 3;
  int t = threadIdx.x;
  {
    int b = t >> 5, k = t & 31;
    us[b][k] = uv[b * HID + kc * 32 + k];
    vs[b][k] = uv[BB * HID + b * HID + kc * 32 + k];
  }
  __syncthreads();
  int f = fc * 64 + (t & 63);
  int ks = t >> 6;                 // 0..3
  float acc[8] = {0, 0, 0, 0, 0, 0, 0, 0};
#pragma unroll
  for (int j = 0; j < 8; ++j) {
    int kl = ks * 8 + j;           // 0..31
    int k = kc * 32 + kl;
    float wr = Wrel3[k * HID + f];
    float wo = Wroot3[k * HID + f];
#pragma unroll
    for (int b = 0; b < 8; ++b)
      acc[b] += us[b][kl] * wr + vs[b][kl] * wo;
  }
#pragma unroll
  for (int b = 0; b < 8; ++b) red[ks][t & 63][b] = acc[b];
  __syncthreads();
  if (ks == 0) {
    int fl = t & 63;
#pragma unroll
    for (int b = 0; b < 8; ++b) {
      float v = red[0][fl][b] + red[1][fl][b] + red[2][fl][b] + red[3][fl][b];
      atomicAdd(&xmacc[b * HID + f], v);
    }
  }
}

// ---------------------------------------------------------------------------
// Kernel G3: lin1 split-K partials; xm = 0.5*xmacc + brel3 at staging.
// ---------------------------------------------------------------------------
__global__ __launch_bounds__(256) void lin1_part(
    const float* __restrict__ xmacc, const float* __restrict__ brel3,
    const float* __restrict__ Wlin1, float* __restrict__ h2acc) {
  __shared__ float xs[8][32];
  __shared__ float red[4][64][8];
  int blk = blockIdx.x;
  int fc = blk & 7, kc = blk >> 3;
  int t = threadIdx.x;
  {
    int b = t >> 5, k = t & 31;
    xs[b][k] = 0.5f * xmacc[b * HID + kc * 32 + k] + brel3[kc * 32 + k];
  }
  __syncthreads();
  int f = fc * 64 + (t & 63);
  int ks = t >> 6;
  float acc[8] = {0, 0, 0, 0, 0, 0, 0, 0};
#pragma unroll
  for (int j = 0; j < 8; ++j) {
    int kl = ks * 8 + j;
    int k = kc * 32 + kl;
    float w = Wlin1[k * HID + f];
#pragma unroll
    for (int b = 0; b < 8; ++b)
      acc[b] += xs[b][kl] * w;
  }
#pragma unroll
  for (int b = 0; b < 8; ++b) red[ks][t & 63][b] = acc[b];
  __syncthreads();
  if (ks == 0) {
    int fl = t & 63;
#pragma unroll
    for (int b = 0; b < 8; ++b) {
      float v = red[0][fl][b] + red[1][fl][b] + red[2][fl][b] + red[3][fl][b];
      atomicAdd(&h2acc[b * HID + f], v);
    }
  }
}

// ---------------------------------------------------------------------------
// Kernel G4: logits + log_softmax; h2 = relu(h2acc + blin1) at staging.
// Block 0 additionally sums the per-graph loss partials into dout[80,81].
// ---------------------------------------------------------------------------
__global__ __launch_bounds__(256) void head(
    const float* __restrict__ h2acc, const float* __restrict__ blin1,
    const float* __restrict__ Wlin2, const float* __restrict__ blin2,
    const float* __restrict__ lossp, float* __restrict__ dout) {
  __shared__ float hs[HID];
  __shared__ float lg[16];
  __shared__ float lse;
  int b = blockIdx.x, t = threadIdx.x;
  if (b == 0 && t == 255) {
    float l0 = 0.f, l1 = 0.f;
#pragma unroll
    for (int i = 0; i < BB; ++i) { l0 += lossp[i * 2]; l1 += lossp[i * 2 + 1]; }
    dout[80] = l0;
    dout[81] = l1;
  }
  for (int i = t; i < HID; i += 256)
    hs[i] = fmaxf(h2acc[b * HID + i] + blin1[i], 0.f);
  __syncthreads();
  int wave = t >> 6, lane = t & 63;
  for (int o = wave; o < OUTC; o += 4) {
    float acc = 0.f;
    for (int k = lane; k < HID; k += 64)
      acc += hs[k] * Wlin2[k * OUTC + o];
#pragma unroll
    for (int off = 32; off; off >>= 1) acc += __shfl_down(acc, off, 64);
    if (lane == 0) lg[o] = acc + blin2[o];
  }
  __syncthreads();
  if (t == 0) {
    float m = lg[0];
    for (int o = 1; o < OUTC; ++o) m = fmaxf(m, lg[o]);
    float se = 0.f;
    for (int o = 0; o < OUTC; ++o) se += expf(lg[o] - m);
    lse = m + logf(se);
  }
  __syncthreads();
  if (t < OUTC) dout[b * OUTC + t] = lg[t] - lse;
}

// ---------------------------------------------------------------------------
// Launcher
// ---------------------------------------------------------------------------
extern "C" void kernel_launch(void* const* d_in, const int* in_sizes, int n_in,
                              void* d_out, int out_size, void* d_ws, size_t ws_size,
                              hipStream_t stream) {
  const float* x      = (const float*)d_in[0];
  const int*   ei     = (const int*)d_in[1];
  const float* ew     = (const float*)d_in[3];
  const float* Wrel1  = (const float*)d_in[4];
  const float* brel1  = (const float*)d_in[5];
  const float* Wroot1 = (const float*)d_in[6];
  const float* Wpool  = (const float*)d_in[7];
  const float* bpool  = (const float*)d_in[8];
  const float* Wrel3  = (const float*)d_in[9];
  const float* brel3  = (const float*)d_in[10];
  const float* Wroot3 = (const float*)d_in[11];
  const float* Wlin1  = (const float*)d_in[12];
  const float* blin1  = (const float*)d_in[13];
  const float* Wlin2  = (const float*)d_in[14];
  const float* blin2  = (const float*)d_in[15];
  float* out = (float*)d_out;
  float* ws  = (float*)d_ws;

  // workspace layout (float units) — zero region is one contiguous block:
  //   [40960, 81992): oadj, ssacc, mden, deg, xmacc, h2acc
  float* oadj  = ws + 40960;                // [40960, 40992)
  float* ssacc = oadj + 32;                 // [40992, 41024)
  float* mden  = ssacc + 32;                // [41024, 41032)
  int*   deg   = (int*)(mden + 8);          // [41032, 73800)
  float* xmacc = ws + 73800;                // [73800, 77896)
  float* h2acc = xmacc + 4096;              // [77896, 81992)  zero-region end
  float* lossp = ws + 81992;                // [81992, 82008)  written each run
  ushort* Ab   = (ushort*)(ws + 106568);    // 32768x256 bf16  [106568, 4300872)
  ushort* Bb   = (ushort*)(ws + 4300872);   // 512x256 bf16    [4300872, 4366408)
  float* outpart = ws + 12763208;           // 512*1024        [12763208, 13287496)
  float* s     = ws + 16000000;             // 32768x2 fp32    [16000000, 16065536)
  // aliases (lifetimes by stream order):
  int2*  ell   = (int2*)(ws + 4366408);     // 16.8MB, dead after gather_ell
  float* uv    = (float*)deg;               // deg dead after gather_ell

  const int* src = ei;
  const int* dst = ei + BE;

  hipMemsetAsync(ws + 40960, 0, (size_t)41032 * sizeof(float), stream);

  front      <<<6656, 256, 0, stream>>>(src, dst, ew, x, Wrel1, Wroot1,
                                        deg, ell, Ab, Bb);
  gather_ell <<<BN / 4, 256, 0, stream>>>(deg, ell, Ab);
  gemm_pool  <<<512, 256, 0, stream>>>(Ab, Bb, brel1, Wpool, bpool,
                                       s, out + 82, outpart, ssacc);
  edge_pass2 <<<BB * 64, 256, 0, stream>>>(src, dst, ew, s, oadj, mden);
  finalize_a <<<64, 256, 0, stream>>>(outpart, oadj, ssacc, mden, uv, lossp, out);
  conv3_part <<<128, 256, 0, stream>>>(uv, Wrel3, Wroot3, xmacc);
  lin1_part  <<<128, 256, 0, stream>>>(xmacc, brel3, Wlin1, h2acc);
  head       <<<BB, 256, 0, stream>>>(h2acc, blin1, Wlin2, blin2, lossp, out);
}

// Round 11
// 213.818 us; speedup vs baseline: 1.0762x; 1.0762x over previous
//
#include <hip/hip_runtime.h>
#include <hip/hip_bf16.h>

// Problem constants
#define BB 8
#define NN 4096
#define EE 65536            // edges per graph
#define BE (BB*EE)          // 524288 total edges
#define BN (BB*NN)          // 32768 total nodes
#define INF 128
#define HID 512
#define CC 2
#define OUTC 10
#define ELLCAP 64           // max in-degree capacity (Binomial mean 16, P(>=64)<1e-13)

typedef __bf16 bf16x8_t __attribute__((ext_vector_type(8)));
typedef float  f32x4_t  __attribute__((ext_vector_type(4)));

__device__ __forceinline__ ushort f2bf(float f) {
  union { float f; unsigned u; } v; v.f = f;
  unsigned r = v.u + 0x7FFFu + ((v.u >> 16) & 1u);   // RNE
  return (ushort)(r >> 16);
}
__device__ __forceinline__ float bf2f(ushort s) {
  union { unsigned u; float f; } v; v.u = ((unsigned)s) << 16;
  return v.f;
}

// ---------------------------------------------------------------------------
// Kernel FRONT (fused): three independent prep stages in one launch.
// XCD-locality: for cast_x and ell_build, blk&7 selects the GRAPH.
// ---------------------------------------------------------------------------
__global__ __launch_bounds__(256) void front(
    const int* __restrict__ src, const int* __restrict__ dst,
    const float* __restrict__ ew, const float* __restrict__ x,
    const float* __restrict__ Wrel, const float* __restrict__ Wroot,
    int* __restrict__ deg, int2* __restrict__ ell,
    ushort* __restrict__ Ab, ushort* __restrict__ Bb) {
  int blk = blockIdx.x;
  int tid = threadIdx.x;
  if (blk < 4096) {
    int g = (blk & 7) * 131072 + (blk >> 3) * 256 + tid;   // 0..1048575
    float4 v = *(const float4*)&x[(size_t)g * 4];
    int m = g >> 5;
    int kin = (g & 31) * 4;
    ushort4 o;
    o.x = f2bf(v.x); o.y = f2bf(v.y); o.z = f2bf(v.z); o.w = f2bf(v.w);
    *(ushort4*)&Ab[(size_t)m * 256 + 128 + kin] = o;
  } else if (blk < 6144) {
    int bl = blk - 4096;                       // 0..2047 (2048 ≡ 0 mod 8)
    int e = (bl & 7) * EE + (bl >> 3) * 256 + tid;   // 0..524287
    int d = dst[e];
    int p = atomicAdd(&deg[d], 1);
    if (p < ELLCAP) {
      int2 v; v.x = src[e]; v.y = __float_as_int(ew[e]);
      ell[(size_t)d * ELLCAP + p] = v;
    }
  } else {
    int g = (blk - 6144) * 256 + tid;          // 0..131071
    int n = g & 511, k = g >> 9;
    float w = (k < 128) ? Wrel[k * 512 + n] : Wroot[(k - 128) * 512 + n];
    Bb[n * 256 + k] = f2bf(w);
  }
}

// ---------------------------------------------------------------------------
// Kernel A5: gather  A[n, 0:128] = bf16( sum_j w_j * xbf16[src_j,:] )
// One node per WAVE; 4 edges/iter, uint4 feature slices. blk&7 = graph.
// ---------------------------------------------------------------------------
__global__ __launch_bounds__(256) void gather_ell(
    const int* __restrict__ deg, const int2* __restrict__ ell,
    ushort* __restrict__ Ab) {
  int blk = blockIdx.x;
  int n = (blk & 7) * NN + (blk >> 3) * 4 + (threadIdx.x >> 6);
  int lane = threadIdx.x & 63;
  int l4 = lane >> 4;          // edge slot 0..3
  int fl = lane & 15;          // feature slice
  int d = deg[n]; if (d > ELLCAP) d = ELLCAP;
  const int2* ep = ell + (size_t)n * ELLCAP;

  float a[8] = {0, 0, 0, 0, 0, 0, 0, 0};
  int j = 0;
  for (; j + 7 < d; j += 8) {
    int2 v0 = ep[j + l4];
    int2 v1 = ep[j + 4 + l4];
    uint4 u0 = *(const uint4*)&Ab[(size_t)v0.x * 256 + 128 + fl * 8];
    uint4 u1 = *(const uint4*)&Ab[(size_t)v1.x * 256 + 128 + fl * 8];
    float w0 = __int_as_float(v0.y);
    float w1 = __int_as_float(v1.y);
    const ushort* s0 = (const ushort*)&u0;
    const ushort* s1 = (const ushort*)&u1;
#pragma unroll
    for (int q = 0; q < 8; ++q)
      a[q] += w0 * bf2f(s0[q]) + w1 * bf2f(s1[q]);
  }
  for (; j + 3 < d; j += 4) {
    int2 v0 = ep[j + l4];
    uint4 u0 = *(const uint4*)&Ab[(size_t)v0.x * 256 + 128 + fl * 8];
    float w0 = __int_as_float(v0.y);
    const ushort* s0 = (const ushort*)&u0;
#pragma unroll
    for (int q = 0; q < 8; ++q)
      a[q] += w0 * bf2f(s0[q]);
  }
  {
    int idx = j + l4;
    if (idx < d) {
      int2 v0 = ep[idx];
      uint4 u0 = *(const uint4*)&Ab[(size_t)v0.x * 256 + 128 + fl * 8];
      float w0 = __int_as_float(v0.y);
      const ushort* s0 = (const ushort*)&u0;
#pragma unroll
      for (int q = 0; q < 8; ++q)
        a[q] += w0 * bf2f(s0[q]);
    }
  }
#pragma unroll
  for (int q = 0; q < 8; ++q) {
    a[q] += __shfl_xor(a[q], 16, 64);
    a[q] += __shfl_xor(a[q], 32, 64);
  }
  if (l4 == 0) {
    ushort o[8];
#pragma unroll
    for (int q = 0; q < 8; ++q) o[q] = f2bf(a[q]);
    *(uint4*)&Ab[(size_t)n * 256 + fl * 8] = *(const uint4*)o;
  }
}

// ---------------------------------------------------------------------------
// Kernel CP4: gemm_pool, L2-bounce version (R10 post-mortem fix).
// 512 blocks (blk&7 = graph = XCD), 64-row strip per block.
// Pass 1 (8 heavy phases, was 16): stage Bs, MFMA, h -> logit partials AND
//   LDS bounce hC (stride 72: aligned uint4, low-conflict) -> coalesced
//   global store to hbf (graph-local -> stays in this XCD's L2, 4MB/graph).
// Pass 2: light register sweep o = s^T h reading hbf back from L2 — no B
//   re-stage, no second MFMA. Per-wave outpart slices (no LDS oacc).
// LDS 77.5 KB -> 2 blocks/CU. VGPR back to ~R9 level (no hpk).
// ---------------------------------------------------------------------------
__global__ __launch_bounds__(256) void gemm_pool(
    const ushort* __restrict__ Ab, const ushort* __restrict__ Bb,
    const float* __restrict__ brel, const float* __restrict__ Wp,
    const float* __restrict__ bp, ushort* __restrict__ hbf,
    float* __restrict__ s, float* __restrict__ slog,
    float* __restrict__ outpart, float* __restrict__ ssacc) {
  __shared__ ushort As[64 * 256];   // 32 KB
  __shared__ ushort Bs[64 * 256];   // 32 KB
  __shared__ ushort hC[64 * 72];    // 9 KB  h-chunk bounce
  __shared__ float brS[512];        // 2 KB
  __shared__ float2 ssv[64];        // 512 B
  __shared__ float ssrw[16][3];     // 192 B
  int tid = threadIdx.x;
  int blk = blockIdx.x;
  int b = blk & 7;                  // graph = XCD
  int chunk = blk >> 3;             // 0..63
  int m0 = b * NN + chunk * 64;
  int obik = b * 64 + chunk;

  // stage As once (coalesced, XOR-swizzled) + brel
#pragma unroll
  for (int i = 0; i < 8; ++i) {
    int g = tid + i * 256;
    int r = g >> 5, c = g & 31;
    int cs = c ^ (r & 31);
    *(uint4*)&As[(r * 32 + cs) * 8] = *(const uint4*)&Ab[(size_t)(m0 + r) * 256 + c * 8];
  }
  if (tid < 128) *(float4*)&brS[tid * 4] = *(const float4*)&brel[tid * 4];

  int wave = tid >> 6, lane = tid & 63;
  int wm = wave * 16;
  int l16 = lane & 15, quad = lane >> 4;
  int arow = wm + l16;
  float bp0 = bp[0], bp1 = bp[1];

  float la0[4] = {0, 0, 0, 0}, la1[4] = {0, 0, 0, 0};

  // ---------------- pass 1: GEMM + logit partials + h bounce ----------------
  for (int cc = 0; cc < 8; ++cc) {
    int n0 = cc * 64;
#pragma unroll
    for (int i = 0; i < 8; ++i) {
      int g = tid + i * 256;
      int r = g >> 5, c = g & 31;
      int cs = c ^ (r & 31);
      *(uint4*)&Bs[(r * 32 + cs) * 8] = *(const uint4*)&Bb[(size_t)(n0 + r) * 256 + c * 8];
    }
    __syncthreads();   // Bs ready; prev chunk's hC reads complete

    f32x4_t acc[4];
#pragma unroll
    for (int ct = 0; ct < 4; ++ct) acc[ct] = (f32x4_t){0.f, 0.f, 0.f, 0.f};
#pragma unroll
    for (int kc = 0; kc < 8; ++kc) {
      int cl = kc * 4 + quad;
      bf16x8_t af = *(const bf16x8_t*)&As[(arow * 32 + (cl ^ (arow & 31))) * 8];
#pragma unroll
      for (int ct = 0; ct < 4; ++ct) {
        int brow = ct * 16 + l16;
        bf16x8_t bf = *(const bf16x8_t*)&Bs[(brow * 32 + (cl ^ (brow & 31))) * 8];
        acc[ct] = __builtin_amdgcn_mfma_f32_16x16x32_bf16(af, bf, acc[ct], 0, 0, 0);
      }
    }
#pragma unroll
    for (int ct = 0; ct < 4; ++ct) {
      int col = n0 + ct * 16 + l16;
      float bias = brS[col];
      float w0 = Wp[col * 2], w1 = Wp[col * 2 + 1];
      int rowb = wm + quad * 4;
      float h0 = fmaxf(acc[ct][0] + bias, 0.f);
      float h1 = fmaxf(acc[ct][1] + bias, 0.f);
      float h2 = fmaxf(acc[ct][2] + bias, 0.f);
      float h3 = fmaxf(acc[ct][3] + bias, 0.f);
      la0[0] += h0 * w0; la1[0] += h0 * w1;
      la0[1] += h1 * w0; la1[1] += h1 * w1;
      la0[2] += h2 * w0; la1[2] += h2 * w1;
      la0[3] += h3 * w0; la1[3] += h3 * w1;
      int cbase = ct * 16 + l16;
      hC[(rowb + 0) * 72 + cbase] = f2bf(h0);
      hC[(rowb + 1) * 72 + cbase] = f2bf(h1);
      hC[(rowb + 2) * 72 + cbase] = f2bf(h2);
      hC[(rowb + 3) * 72 + cbase] = f2bf(h3);
    }
    __syncthreads();   // hC complete, Bs consumed
    // coalesced store hC -> hbf (graph-local, lands in XCD L2)
    {
      int r = tid >> 2, co = (tid & 3) * 16;
      uint4 v0 = *(uint4*)&hC[r * 72 + co];
      uint4 v1 = *(uint4*)&hC[r * 72 + co + 8];
      *(uint4*)&hbf[(size_t)(m0 + r) * 512 + n0 + co] = v0;
      *(uint4*)&hbf[(size_t)(m0 + r) * 512 + n0 + co + 8] = v1;
    }
  }

  // reduce logits over the 16 l16 lanes (cols) within each quad group
#pragma unroll
  for (int r = 0; r < 4; ++r) {
#pragma unroll
    for (int m = 1; m < 16; m <<= 1) {
      la0[r] += __shfl_xor(la0[r], m, 64);
      la1[r] += __shfl_xor(la1[r], m, 64);
    }
  }
  if (l16 == 0) {
    float sa = 0.f, sb = 0.f, sc2 = 0.f;
#pragma unroll
    for (int r = 0; r < 4; ++r) {
      int row = wm + quad * 4 + r;
      int n = m0 + row;
      float l0 = la0[r] + bp0, l1 = la1[r] + bp1;
      slog[n * 2] = l0;
      slog[n * 2 + 1] = l1;
      float mm = fmaxf(l0, l1);
      float e0 = expf(l0 - mm), e1 = expf(l1 - mm);
      float inv = 1.f / (e0 + e1);
      float s0 = e0 * inv, s1 = e1 * inv;
      *(float2*)&s[n * 2] = make_float2(s0, s1);
      ssv[row] = make_float2(s0, s1);
      sa += s0 * s0; sb += s0 * s1; sc2 += s1 * s1;
    }
    int idx = wave * 4 + quad;
    ssrw[idx][0] = sa; ssrw[idx][1] = sb; ssrw[idx][2] = sc2;
  }
  __syncthreads();   // ssv visible; hbf stores drained (waitcnt before barrier)

  // ---------------- pass 2: light sweep o = s^T h from L2 ----------------
  {
    int f0 = lane * 8;
    float o0[8] = {0, 0, 0, 0, 0, 0, 0, 0};
    float o1[8] = {0, 0, 0, 0, 0, 0, 0, 0};
    for (int i = 0; i < 16; ++i) {
      int row = wm + i;
      float2 sv = ssv[row];
      bf16x8_t hv = *(const bf16x8_t*)&hbf[(size_t)(m0 + row) * 512 + f0];
      const ushort* hp = (const ushort*)&hv;
#pragma unroll
      for (int j = 0; j < 8; ++j) {
        float h = bf2f(hp[j]);
        o0[j] += sv.x * h;
        o1[j] += sv.y * h;
      }
    }
    size_t base = (size_t)(obik * 4 + wave) * 1024;
    *(float4*)&outpart[base + f0]       = *(float4*)&o0[0];
    *(float4*)&outpart[base + f0 + 4]   = *(float4*)&o0[4];
    *(float4*)&outpart[base + 512 + f0]     = *(float4*)&o1[0];
    *(float4*)&outpart[base + 512 + f0 + 4] = *(float4*)&o1[4];
  }
  if (tid < 3) {
    float v = 0.f;
#pragma unroll
    for (int i = 0; i < 16; ++i) v += ssrw[i][tid];
    atomicAdd(&ssacc[b * 4 + tid], v);
  }
}

// ---------------------------------------------------------------------------
// Kernel E: out_adj_raw[b,i,j] = sum_e w_e * s[src,i] * s[dst,j]
// + mincut_den[b]. XCD-locality: blk&7 = graph.
// ---------------------------------------------------------------------------
__global__ __launch_bounds__(256) void edge_pass2(
    const int* __restrict__ src, const int* __restrict__ dst,
    const float* __restrict__ ew, const float* __restrict__ s,
    float* __restrict__ oadj, float* __restrict__ mden) {
  int b = blockIdx.x & 7;
  int sub = blockIdx.x >> 3;
  int base = b * EE + sub * 1024;
  float p00 = 0, p01 = 0, p10 = 0, p11 = 0, md = 0;
  for (int i = threadIdx.x; i < 1024; i += 256) {
    int e = base + i;
    int r = src[e], c = dst[e];
    float w = ew[e];
    float s0r = s[r * 2], s1r = s[r * 2 + 1];
    float s0c = s[c * 2], s1c = s[c * 2 + 1];
    p00 += w * s0r * s0c; p01 += w * s0r * s1c;
    p10 += w * s1r * s0c; p11 += w * s1r * s1c;
    md  += w * (s0r * s0r + s1r * s1r);
  }
#pragma unroll
  for (int off = 32; off; off >>= 1) {
    p00 += __shfl_down(p00, off, 64);
    p01 += __shfl_down(p01, off, 64);
    p10 += __shfl_down(p10, off, 64);
    p11 += __shfl_down(p11, off, 64);
    md  += __shfl_down(md,  off, 64);
  }
  __shared__ float red[4][5];
  int wave = threadIdx.x >> 6, lane = threadIdx.x & 63;
  if (lane == 0) {
    red[wave][0] = p00; red[wave][1] = p01;
    red[wave][2] = p10; red[wave][3] = p11;
    red[wave][4] = md;
  }
  __syncthreads();
  if (threadIdx.x < 4) {
    float v = red[0][threadIdx.x] + red[1][threadIdx.x] +
              red[2][threadIdx.x] + red[3][threadIdx.x];
    atomicAdd(&oadj[b * 4 + threadIdx.x], v);
  } else if (threadIdx.x == 4) {
    float v = red[0][4] + red[1][4] + red[2][4] + red[3][4];
    atomicAdd(&mden[b], v);
  }
}

// ---------------------------------------------------------------------------
// Kernel G1: per-graph scalars + u,v build. 64 blocks = b(8) x fc(8).
// outpart now has 256 per-wave slices per graph (4 per 64-row strip).
// ---------------------------------------------------------------------------
__global__ __launch_bounds__(256) void finalize_a(
    const float* __restrict__ outpart, const float* __restrict__ oadj,
    const float* __restrict__ ssacc, const float* __restrict__ mden,
    float* __restrict__ uv, float* __restrict__ lossp,
    float* __restrict__ dout) {
  __shared__ float sc[2];
  __shared__ float r0[256], r1[256];
  int b = blockIdx.x >> 3, fc = blockIdx.x & 7;
  int t = threadIdx.x;
  if (t == 0) {
    float r00 = oadj[b * 4 + 0], r01 = oadj[b * 4 + 1];
    float r10 = oadj[b * 4 + 2], r11 = oadj[b * 4 + 3];
    float d20 = sqrtf(r01) + 1e-15f;
    float d21 = sqrtf(r10) + 1e-15f;
    float oa01 = r01 / (d20 * d21);
    float oa10 = r10 / (d21 * d20);
    sc[0] = oa01; sc[1] = oa10;
    if (fc == 0) {
      lossp[b * 2 + 0] = -((r00 + r11) / mden[b]) / (float)BB;
      float a = ssacc[b * 4 + 0], bb = ssacc[b * 4 + 1], c = ssacc[b * 4 + 2];
      float nrm = sqrtf(a * a + 2.f * bb * bb + c * c);
      float q = 0.70710678118654752f;
      float da = a / nrm - q, db = bb / nrm, dc = c / nrm - q;
      lossp[b * 2 + 1] = sqrtf(da * da + 2.f * db * db + dc * dc) / (float)BB;
      dout[65618 + b * 4 + 0] = 0.f;
      dout[65618 + b * 4 + 1] = oa01;
      dout[65618 + b * 4 + 2] = oa10;
      dout[65618 + b * 4 + 3] = 0.f;
    }
  }
  __syncthreads();
  int f = fc * 64 + (t & 63);
  int ic = t >> 6;                         // 0..3 -> 64 slices each
  float o0s = 0.f, o1s = 0.f;
  for (int i = ic * 64; i < ic * 64 + 64; ++i) {
    o0s += outpart[(size_t)(b * 256 + i) * 1024 + f];
    o1s += outpart[(size_t)(b * 256 + i) * 1024 + 512 + f];
  }
  r0[ic * 64 + (t & 63)] = o0s;
  r1[ic * 64 + (t & 63)] = o1s;
  __syncthreads();
  if (ic == 0) {
    int fl = t & 63;
    float a0 = r0[fl] + r0[64 + fl] + r0[128 + fl] + r0[192 + fl];
    float a1 = r1[fl] + r1[64 + fl] + r1[128 + fl] + r1[192 + fl];
    uv[b * HID + f] = sc[1] * a1 + sc[0] * a0;   // u = oa10*o1 + oa01*o0
    uv[BB * HID + b * HID + f] = a0 + a1;        // v
  }
}

// ---------------------------------------------------------------------------
// Kernel G2: conv3 split-K partials. Grid 128 = kc(16) x fc(8).
// ---------------------------------------------------------------------------
__global__ __launch_bounds__(256) void conv3_part(
    const float* __restrict__ uv, const float* __restrict__ Wrel3,
    const float* __restrict__ Wroot3, float* __restrict__ xmacc) {
  __shared__ float us[8][32], vs[8][32];
  __shared__ float red[4][64][8];
  int blk = blockIdx.x;
  int fc = blk & 7, kc = blk >> 3;
  int t = threadIdx.x;
  {
    int b = t >> 5, k = t & 31;
    us[b][k] = uv[b * HID + kc * 32 + k];
    vs[b][k] = uv[BB * HID + b * HID + kc * 32 + k];
  }
  __syncthreads();
  int f = fc * 64 + (t & 63);
  int ks = t >> 6;                 // 0..3
  float acc[8] = {0, 0, 0, 0, 0, 0, 0, 0};
#pragma unroll
  for (int j = 0; j < 8; ++j) {
    int kl = ks * 8 + j;           // 0..31
    int k = kc * 32 + kl;
    float wr = Wrel3[k * HID + f];
    float wo = Wroot3[k * HID + f];
#pragma unroll
    for (int b = 0; b < 8; ++b)
      acc[b] += us[b][kl] * wr + vs[b][kl] * wo;
  }
#pragma unroll
  for (int b = 0; b < 8; ++b) red[ks][t & 63][b] = acc[b];
  __syncthreads();
  if (ks == 0) {
    int fl = t & 63;
#pragma unroll
    for (int b = 0; b < 8; ++b) {
      float v = red[0][fl][b] + red[1][fl][b] + red[2][fl][b] + red[3][fl][b];
      atomicAdd(&xmacc[b * HID + f], v);
    }
  }
}

// ---------------------------------------------------------------------------
// Kernel G3: lin1 split-K partials; xm = 0.5*xmacc + brel3 at staging.
// ---------------------------------------------------------------------------
__global__ __launch_bounds__(256) void lin1_part(
    const float* __restrict__ xmacc, const float* __restrict__ brel3,
    const float* __restrict__ Wlin1, float* __restrict__ h2acc) {
  __shared__ float xs[8][32];
  __shared__ float red[4][64][8];
  int blk = blockIdx.x;
  int fc = blk & 7, kc = blk >> 3;
  int t = threadIdx.x;
  {
    int b = t >> 5, k = t & 31;
    xs[b][k] = 0.5f * xmacc[b * HID + kc * 32 + k] + brel3[kc * 32 + k];
  }
  __syncthreads();
  int f = fc * 64 + (t & 63);
  int ks = t >> 6;
  float acc[8] = {0, 0, 0, 0, 0, 0, 0, 0};
#pragma unroll
  for (int j = 0; j < 8; ++j) {
    int kl = ks * 8 + j;
    int k = kc * 32 + kl;
    float w = Wlin1[k * HID + f];
#pragma unroll
    for (int b = 0; b < 8; ++b)
      acc[b] += xs[b][kl] * w;
  }
#pragma unroll
  for (int b = 0; b < 8; ++b) red[ks][t & 63][b] = acc[b];
  __syncthreads();
  if (ks == 0) {
    int fl = t & 63;
#pragma unroll
    for (int b = 0; b < 8; ++b) {
      float v = red[0][fl][b] + red[1][fl][b] + red[2][fl][b] + red[3][fl][b];
      atomicAdd(&h2acc[b * HID + f], v);
    }
  }
}

// ---------------------------------------------------------------------------
// Kernel G4: logits + log_softmax; h2 = relu(h2acc + blin1) at staging.
// Block 0 additionally sums the per-graph loss partials into dout[80,81].
// ---------------------------------------------------------------------------
__global__ __launch_bounds__(256) void head(
    const float* __restrict__ h2acc, const float* __restrict__ blin1,
    const float* __restrict__ Wlin2, const float* __restrict__ blin2,
    const float* __restrict__ lossp, float* __restrict__ dout) {
  __shared__ float hs[HID];
  __shared__ float lg[16];
  __shared__ float lse;
  int b = blockIdx.x, t = threadIdx.x;
  if (b == 0 && t == 255) {
    float l0 = 0.f, l1 = 0.f;
#pragma unroll
    for (int i = 0; i < BB; ++i) { l0 += lossp[i * 2]; l1 += lossp[i * 2 + 1]; }
    dout[80] = l0;
    dout[81] = l1;
  }
  for (int i = t; i < HID; i += 256)
    hs[i] = fmaxf(h2acc[b * HID + i] + blin1[i], 0.f);
  __syncthreads();
  int wave = t >> 6, lane = t & 63;
  for (int o = wave; o < OUTC; o += 4) {
    float acc = 0.f;
    for (int k = lane; k < HID; k += 64)
      acc += hs[k] * Wlin2[k * OUTC + o];
#pragma unroll
    for (int off = 32; off; off >>= 1) acc += __shfl_down(acc, off, 64);
    if (lane == 0) lg[o] = acc + blin2[o];
  }
  __syncthreads();
  if (t == 0) {
    float m = lg[0];
    for (int o = 1; o < OUTC; ++o) m = fmaxf(m, lg[o]);
    float se = 0.f;
    for (int o = 0; o < OUTC; ++o) se += expf(lg[o] - m);
    lse = m + logf(se);
  }
  __syncthreads();
  if (t < OUTC) dout[b * OUTC + t] = lg[t] - lse;
}

// ---------------------------------------------------------------------------
// Launcher
// ---------------------------------------------------------------------------
extern "C" void kernel_launch(void* const* d_in, const int* in_sizes, int n_in,
                              void* d_out, int out_size, void* d_ws, size_t ws_size,
                              hipStream_t stream) {
  const float* x      = (const float*)d_in[0];
  const int*   ei     = (const int*)d_in[1];
  const float* ew     = (const float*)d_in[3];
  const float* Wrel1  = (const float*)d_in[4];
  const float* brel1  = (const float*)d_in[5];
  const float* Wroot1 = (const float*)d_in[6];
  const float* Wpool  = (const float*)d_in[7];
  const float* bpool  = (const float*)d_in[8];
  const float* Wrel3  = (const float*)d_in[9];
  const float* brel3  = (const float*)d_in[10];
  const float* Wroot3 = (const float*)d_in[11];
  const float* Wlin1  = (const float*)d_in[12];
  const float* blin1  = (const float*)d_in[13];
  const float* Wlin2  = (const float*)d_in[14];
  const float* blin2  = (const float*)d_in[15];
  float* out = (float*)d_out;
  float* ws  = (float*)d_ws;

  // workspace layout (float units) — zero region is one contiguous block:
  //   [40960, 81992): oadj, ssacc, mden, deg, xmacc, h2acc
  float* oadj  = ws + 40960;                // [40960, 40992)
  float* ssacc = oadj + 32;                 // [40992, 41024)
  float* mden  = ssacc + 32;                // [41024, 41032)
  int*   deg   = (int*)(mden + 8);          // [41032, 73800)
  float* xmacc = ws + 73800;                // [73800, 77896)
  float* h2acc = xmacc + 4096;              // [77896, 81992)  zero-region end
  float* lossp = ws + 81992;                // [81992, 82008)  written each run
  ushort* Ab   = (ushort*)(ws + 106568);    // 32768x256 bf16  [106568, 4300872)
  ushort* Bb   = (ushort*)(ws + 4300872);   // 512x256 bf16    [4300872, 4366408)
  ushort* hbf  = (ushort*)(ws + 4366408);   // 32768x512 bf16  [4366408, 12755016)
  float* outpart = ws + 12763208;           // 2048*1024       [12763208, 14860360)
  float* s     = ws + 16000000;             // 32768x2 fp32    [16000000, 16065536)
  // aliases (lifetimes by stream order):
  int2*  ell   = (int2*)(ws + 4366408);     // 16.8MB inside hbf region, dead pre-gemm
  float* uv    = (float*)deg;               // deg dead after gather_ell

  const int* src = ei;
  const int* dst = ei + BE;

  hipMemsetAsync(ws + 40960, 0, (size_t)41032 * sizeof(float), stream);

  front      <<<6656, 256, 0, stream>>>(src, dst, ew, x, Wrel1, Wroot1,
                                        deg, ell, Ab, Bb);
  gather_ell <<<BN / 4, 256, 0, stream>>>(deg, ell, Ab);
  gemm_pool  <<<512, 256, 0, stream>>>(Ab, Bb, brel1, Wpool, bpool, hbf,
                                       s, out + 82, outpart, ssacc);
  edge_pass2 <<<BB * 64, 256, 0, stream>>>(src, dst, ew, s, oadj, mden);
  finalize_a <<<64, 256, 0, stream>>>(outpart, oadj, ssacc, mden, uv, lossp, out);
  conv3_part <<<128, 256, 0, stream>>>(uv, Wrel3, Wroot3, xmacc);
  lin1_part  <<<128, 256, 0, stream>>>(xmacc, brel3, Wlin1, h2acc);
  head       <<<BB, 256, 0, stream>>>(h2acc, blin1, Wlin2, blin2, lossp, out);
}

// Round 12
// 192.540 us; speedup vs baseline: 1.1951x; 1.1105x over previous
//
#include <hip/hip_runtime.h>
#include <hip/hip_bf16.h>

// Problem constants
#define BB 8
#define NN 4096
#define EE 65536            // edges per graph
#define BE (BB*EE)          // 524288 total edges
#define BN (BB*NN)          // 32768 total nodes
#define INF 128
#define HID 512
#define CC 2
#define OUTC 10
#define ELLCAP 64           // max in-degree capacity (Binomial mean 16, P(>=64)<1e-13)

typedef __bf16 bf16x8_t __attribute__((ext_vector_type(8)));
typedef float  f32x4_t  __attribute__((ext_vector_type(4)));

__device__ __forceinline__ ushort f2bf(float f) {
  union { float f; unsigned u; } v; v.f = f;
  unsigned r = v.u + 0x7FFFu + ((v.u >> 16) & 1u);   // RNE
  return (ushort)(r >> 16);
}
__device__ __forceinline__ float bf2f(ushort s) {
  union { unsigned u; float f; } v; v.u = ((unsigned)s) << 16;
  return v.f;
}

// ---------------------------------------------------------------------------
// Kernel FRONT (fused): three independent prep stages in one launch.
// XCD-locality: for cast_x and ell_build, blk&7 selects the GRAPH.
// ---------------------------------------------------------------------------
__global__ __launch_bounds__(256) void front(
    const int* __restrict__ src, const int* __restrict__ dst,
    const float* __restrict__ ew, const float* __restrict__ x,
    const float* __restrict__ Wrel, const float* __restrict__ Wroot,
    int* __restrict__ deg, int2* __restrict__ ell,
    ushort* __restrict__ Ab, ushort* __restrict__ Bb) {
  int blk = blockIdx.x;
  int tid = threadIdx.x;
  if (blk < 4096) {
    int g = (blk & 7) * 131072 + (blk >> 3) * 256 + tid;   // 0..1048575
    float4 v = *(const float4*)&x[(size_t)g * 4];
    int m = g >> 5;
    int kin = (g & 31) * 4;
    ushort4 o;
    o.x = f2bf(v.x); o.y = f2bf(v.y); o.z = f2bf(v.z); o.w = f2bf(v.w);
    *(ushort4*)&Ab[(size_t)m * 256 + 128 + kin] = o;
  } else if (blk < 6144) {
    int bl = blk - 4096;                       // 0..2047 (2048 ≡ 0 mod 8)
    int e = (bl & 7) * EE + (bl >> 3) * 256 + tid;   // 0..524287
    int d = dst[e];
    int p = atomicAdd(&deg[d], 1);
    if (p < ELLCAP) {
      int2 v; v.x = src[e]; v.y = __float_as_int(ew[e]);
      ell[(size_t)d * ELLCAP + p] = v;
    }
  } else {
    int g = (blk - 6144) * 256 + tid;          // 0..131071
    int n = g & 511, k = g >> 9;
    float w = (k < 128) ? Wrel[k * 512 + n] : Wroot[(k - 128) * 512 + n];
    Bb[n * 256 + k] = f2bf(w);
  }
}

// ---------------------------------------------------------------------------
// Kernel A5: gather  A[n, 0:128] = bf16( sum_j w_j * xbf16[src_j,:] )
// One node per WAVE; 4 edges/iter, uint4 feature slices. blk&7 = graph.
// ---------------------------------------------------------------------------
__global__ __launch_bounds__(256) void gather_ell(
    const int* __restrict__ deg, const int2* __restrict__ ell,
    ushort* __restrict__ Ab) {
  int blk = blockIdx.x;
  int n = (blk & 7) * NN + (blk >> 3) * 4 + (threadIdx.x >> 6);
  int lane = threadIdx.x & 63;
  int l4 = lane >> 4;          // edge slot 0..3
  int fl = lane & 15;          // feature slice
  int d = deg[n]; if (d > ELLCAP) d = ELLCAP;
  const int2* ep = ell + (size_t)n * ELLCAP;

  float a[8] = {0, 0, 0, 0, 0, 0, 0, 0};
  int j = 0;
  for (; j + 7 < d; j += 8) {
    int2 v0 = ep[j + l4];
    int2 v1 = ep[j + 4 + l4];
    uint4 u0 = *(const uint4*)&Ab[(size_t)v0.x * 256 + 128 + fl * 8];
    uint4 u1 = *(const uint4*)&Ab[(size_t)v1.x * 256 + 128 + fl * 8];
    float w0 = __int_as_float(v0.y);
    float w1 = __int_as_float(v1.y);
    const ushort* s0 = (const ushort*)&u0;
    const ushort* s1 = (const ushort*)&u1;
#pragma unroll
    for (int q = 0; q < 8; ++q)
      a[q] += w0 * bf2f(s0[q]) + w1 * bf2f(s1[q]);
  }
  for (; j + 3 < d; j += 4) {
    int2 v0 = ep[j + l4];
    uint4 u0 = *(const uint4*)&Ab[(size_t)v0.x * 256 + 128 + fl * 8];
    float w0 = __int_as_float(v0.y);
    const ushort* s0 = (const ushort*)&u0;
#pragma unroll
    for (int q = 0; q < 8; ++q)
      a[q] += w0 * bf2f(s0[q]);
  }
  {
    int idx = j + l4;
    if (idx < d) {
      int2 v0 = ep[idx];
      uint4 u0 = *(const uint4*)&Ab[(size_t)v0.x * 256 + 128 + fl * 8];
      float w0 = __int_as_float(v0.y);
      const ushort* s0 = (const ushort*)&u0;
#pragma unroll
      for (int q = 0; q < 8; ++q)
        a[q] += w0 * bf2f(s0[q]);
    }
  }
#pragma unroll
  for (int q = 0; q < 8; ++q) {
    a[q] += __shfl_xor(a[q], 16, 64);
    a[q] += __shfl_xor(a[q], 32, 64);
  }
  if (l4 == 0) {
    ushort o[8];
#pragma unroll
    for (int q = 0; q < 8; ++q) o[q] = f2bf(a[q]);
    *(uint4*)&Ab[(size_t)n * 256 + fl * 8] = *(const uint4*)o;
  }
}

// ---------------------------------------------------------------------------
// Kernel CP5: gemm_pool, L2-bounce + block-reduced outpart (R11 fix).
// 512 blocks (blk&7 = graph = XCD), 64-row strip per block.
// Pass 1 (8 heavy phases): stage Bs, MFMA, logit partials + hC LDS bounce
//   -> coalesced global store to hbf (graph-local, XCD L2).
// Pass 2: light register sweep o = s^T h from L2; then block-level LDS
//   reduction of the 4 wave partials REUSING As (dead after pass 1) so
//   outpart stays 512 slices (R9 layout) — fixes R11's 4x outpart bloat.
// ---------------------------------------------------------------------------
__global__ __launch_bounds__(256) void gemm_pool(
    const ushort* __restrict__ Ab, const ushort* __restrict__ Bb,
    const float* __restrict__ brel, const float* __restrict__ Wp,
    const float* __restrict__ bp, ushort* __restrict__ hbf,
    float* __restrict__ s, float* __restrict__ slog,
    float* __restrict__ outpart, float* __restrict__ ssacc) {
  __shared__ ushort As[64 * 256];   // 32 KB (reused as reduction buf late)
  __shared__ ushort Bs[64 * 256];   // 32 KB
  __shared__ ushort hC[64 * 72];    // 9 KB  h-chunk bounce
  __shared__ float brS[512];        // 2 KB
  __shared__ float2 ssv[64];        // 512 B
  __shared__ float ssrw[16][3];     // 192 B
  int tid = threadIdx.x;
  int blk = blockIdx.x;
  int b = blk & 7;                  // graph = XCD
  int chunk = blk >> 3;             // 0..63
  int m0 = b * NN + chunk * 64;
  int obik = b * 64 + chunk;

  // stage As once (coalesced, XOR-swizzled) + brel
#pragma unroll
  for (int i = 0; i < 8; ++i) {
    int g = tid + i * 256;
    int r = g >> 5, c = g & 31;
    int cs = c ^ (r & 31);
    *(uint4*)&As[(r * 32 + cs) * 8] = *(const uint4*)&Ab[(size_t)(m0 + r) * 256 + c * 8];
  }
  if (tid < 128) *(float4*)&brS[tid * 4] = *(const float4*)&brel[tid * 4];

  int wave = tid >> 6, lane = tid & 63;
  int wm = wave * 16;
  int l16 = lane & 15, quad = lane >> 4;
  int arow = wm + l16;
  float bp0 = bp[0], bp1 = bp[1];

  float la0[4] = {0, 0, 0, 0}, la1[4] = {0, 0, 0, 0};

  // ---------------- pass 1: GEMM + logit partials + h bounce ----------------
  for (int cc = 0; cc < 8; ++cc) {
    int n0 = cc * 64;
#pragma unroll
    for (int i = 0; i < 8; ++i) {
      int g = tid + i * 256;
      int r = g >> 5, c = g & 31;
      int cs = c ^ (r & 31);
      *(uint4*)&Bs[(r * 32 + cs) * 8] = *(const uint4*)&Bb[(size_t)(n0 + r) * 256 + c * 8];
    }
    __syncthreads();   // Bs ready; prev chunk's hC reads complete

    f32x4_t acc[4];
#pragma unroll
    for (int ct = 0; ct < 4; ++ct) acc[ct] = (f32x4_t){0.f, 0.f, 0.f, 0.f};
#pragma unroll
    for (int kc = 0; kc < 8; ++kc) {
      int cl = kc * 4 + quad;
      bf16x8_t af = *(const bf16x8_t*)&As[(arow * 32 + (cl ^ (arow & 31))) * 8];
#pragma unroll
      for (int ct = 0; ct < 4; ++ct) {
        int brow = ct * 16 + l16;
        bf16x8_t bf = *(const bf16x8_t*)&Bs[(brow * 32 + (cl ^ (brow & 31))) * 8];
        acc[ct] = __builtin_amdgcn_mfma_f32_16x16x32_bf16(af, bf, acc[ct], 0, 0, 0);
      }
    }
#pragma unroll
    for (int ct = 0; ct < 4; ++ct) {
      int col = n0 + ct * 16 + l16;
      float bias = brS[col];
      float w0 = Wp[col * 2], w1 = Wp[col * 2 + 1];
      int rowb = wm + quad * 4;
      float h0 = fmaxf(acc[ct][0] + bias, 0.f);
      float h1 = fmaxf(acc[ct][1] + bias, 0.f);
      float h2 = fmaxf(acc[ct][2] + bias, 0.f);
      float h3 = fmaxf(acc[ct][3] + bias, 0.f);
      la0[0] += h0 * w0; la1[0] += h0 * w1;
      la0[1] += h1 * w0; la1[1] += h1 * w1;
      la0[2] += h2 * w0; la1[2] += h2 * w1;
      la0[3] += h3 * w0; la1[3] += h3 * w1;
      int cbase = ct * 16 + l16;
      hC[(rowb + 0) * 72 + cbase] = f2bf(h0);
      hC[(rowb + 1) * 72 + cbase] = f2bf(h1);
      hC[(rowb + 2) * 72 + cbase] = f2bf(h2);
      hC[(rowb + 3) * 72 + cbase] = f2bf(h3);
    }
    __syncthreads();   // hC complete, Bs consumed
    // coalesced store hC -> hbf (graph-local, lands in XCD L2)
    {
      int r = tid >> 2, co = (tid & 3) * 16;
      uint4 v0 = *(uint4*)&hC[r * 72 + co];
      uint4 v1 = *(uint4*)&hC[r * 72 + co + 8];
      *(uint4*)&hbf[(size_t)(m0 + r) * 512 + n0 + co] = v0;
      *(uint4*)&hbf[(size_t)(m0 + r) * 512 + n0 + co + 8] = v1;
    }
  }

  // reduce logits over the 16 l16 lanes (cols) within each quad group
#pragma unroll
  for (int r = 0; r < 4; ++r) {
#pragma unroll
    for (int m = 1; m < 16; m <<= 1) {
      la0[r] += __shfl_xor(la0[r], m, 64);
      la1[r] += __shfl_xor(la1[r], m, 64);
    }
  }
  if (l16 == 0) {
    float sa = 0.f, sb = 0.f, sc2 = 0.f;
#pragma unroll
    for (int r = 0; r < 4; ++r) {
      int row = wm + quad * 4 + r;
      int n = m0 + row;
      float l0 = la0[r] + bp0, l1 = la1[r] + bp1;
      slog[n * 2] = l0;
      slog[n * 2 + 1] = l1;
      float mm = fmaxf(l0, l1);
      float e0 = expf(l0 - mm), e1 = expf(l1 - mm);
      float inv = 1.f / (e0 + e1);
      float s0 = e0 * inv, s1 = e1 * inv;
      *(float2*)&s[n * 2] = make_float2(s0, s1);
      ssv[row] = make_float2(s0, s1);
      sa += s0 * s0; sb += s0 * s1; sc2 += s1 * s1;
    }
    int idx = wave * 4 + quad;
    ssrw[idx][0] = sa; ssrw[idx][1] = sb; ssrw[idx][2] = sc2;
  }
  __syncthreads();   // ssv visible; hbf stores drained; As now dead

  // ---------------- pass 2: light sweep o = s^T h from L2 ----------------
  int f0 = lane * 8;
  float o0[8] = {0, 0, 0, 0, 0, 0, 0, 0};
  float o1[8] = {0, 0, 0, 0, 0, 0, 0, 0};
  for (int i = 0; i < 16; ++i) {
    int row = wm + i;
    float2 sv = ssv[row];
    bf16x8_t hv = *(const bf16x8_t*)&hbf[(size_t)(m0 + row) * 512 + f0];
    const ushort* hp = (const ushort*)&hv;
#pragma unroll
    for (int j = 0; j < 8; ++j) {
      float h = bf2f(hp[j]);
      o0[j] += sv.x * h;
      o1[j] += sv.y * h;
    }
  }
  // block-level reduction of the 4 wave partials, reusing As (16 KB of 32)
  float* red = (float*)As;
#pragma unroll
  for (int j = 0; j < 8; ++j) {
    red[wave * 1024 + f0 + j] = o0[j];
    red[wave * 1024 + 512 + f0 + j] = o1[j];
  }
  __syncthreads();
#pragma unroll
  for (int q = 0; q < 4; ++q) {
    int idx = tid + q * 256;
    float v = red[idx] + red[1024 + idx] + red[2048 + idx] + red[3072 + idx];
    outpart[(size_t)obik * 1024 + idx] = v;
  }
  if (tid < 3) {
    float v = 0.f;
#pragma unroll
    for (int i = 0; i < 16; ++i) v += ssrw[i][tid];
    atomicAdd(&ssacc[b * 4 + tid], v);
  }
}

// ---------------------------------------------------------------------------
// Kernel E: out_adj_raw[b,i,j] = sum_e w_e * s[src,i] * s[dst,j]
// + mincut_den[b]. XCD-locality: blk&7 = graph.
// ---------------------------------------------------------------------------
__global__ __launch_bounds__(256) void edge_pass2(
    const int* __restrict__ src, const int* __restrict__ dst,
    const float* __restrict__ ew, const float* __restrict__ s,
    float* __restrict__ oadj, float* __restrict__ mden) {
  int b = blockIdx.x & 7;
  int sub = blockIdx.x >> 3;
  int base = b * EE + sub * 1024;
  float p00 = 0, p01 = 0, p10 = 0, p11 = 0, md = 0;
  for (int i = threadIdx.x; i < 1024; i += 256) {
    int e = base + i;
    int r = src[e], c = dst[e];
    float w = ew[e];
    float s0r = s[r * 2], s1r = s[r * 2 + 1];
    float s0c = s[c * 2], s1c = s[c * 2 + 1];
    p00 += w * s0r * s0c; p01 += w * s0r * s1c;
    p10 += w * s1r * s0c; p11 += w * s1r * s1c;
    md  += w * (s0r * s0r + s1r * s1r);
  }
#pragma unroll
  for (int off = 32; off; off >>= 1) {
    p00 += __shfl_down(p00, off, 64);
    p01 += __shfl_down(p01, off, 64);
    p10 += __shfl_down(p10, off, 64);
    p11 += __shfl_down(p11, off, 64);
    md  += __shfl_down(md,  off, 64);
  }
  __shared__ float red[4][5];
  int wave = threadIdx.x >> 6, lane = threadIdx.x & 63;
  if (lane == 0) {
    red[wave][0] = p00; red[wave][1] = p01;
    red[wave][2] = p10; red[wave][3] = p11;
    red[wave][4] = md;
  }
  __syncthreads();
  if (threadIdx.x < 4) {
    float v = red[0][threadIdx.x] + red[1][threadIdx.x] +
              red[2][threadIdx.x] + red[3][threadIdx.x];
    atomicAdd(&oadj[b * 4 + threadIdx.x], v);
  } else if (threadIdx.x == 4) {
    float v = red[0][4] + red[1][4] + red[2][4] + red[3][4];
    atomicAdd(&mden[b], v);
  }
}

// ---------------------------------------------------------------------------
// Kernel G1: per-graph scalars + u,v build. 64 blocks = b(8) x fc(8).
// outpart back to 512 slices (64 per graph) — R9-verified version.
// ---------------------------------------------------------------------------
__global__ __launch_bounds__(256) void finalize_a(
    const float* __restrict__ outpart, const float* __restrict__ oadj,
    const float* __restrict__ ssacc, const float* __restrict__ mden,
    float* __restrict__ uv, float* __restrict__ lossp,
    float* __restrict__ dout) {
  __shared__ float sc[2];
  __shared__ float r0[256], r1[256];
  int b = blockIdx.x >> 3, fc = blockIdx.x & 7;
  int t = threadIdx.x;
  if (t == 0) {
    float r00 = oadj[b * 4 + 0], r01 = oadj[b * 4 + 1];
    float r10 = oadj[b * 4 + 2], r11 = oadj[b * 4 + 3];
    float d20 = sqrtf(r01) + 1e-15f;
    float d21 = sqrtf(r10) + 1e-15f;
    float oa01 = r01 / (d20 * d21);
    float oa10 = r10 / (d21 * d20);
    sc[0] = oa01; sc[1] = oa10;
    if (fc == 0) {
      lossp[b * 2 + 0] = -((r00 + r11) / mden[b]) / (float)BB;
      float a = ssacc[b * 4 + 0], bb = ssacc[b * 4 + 1], c = ssacc[b * 4 + 2];
      float nrm = sqrtf(a * a + 2.f * bb * bb + c * c);
      float q = 0.70710678118654752f;
      float da = a / nrm - q, db = bb / nrm, dc = c / nrm - q;
      lossp[b * 2 + 1] = sqrtf(da * da + 2.f * db * db + dc * dc) / (float)BB;
      dout[65618 + b * 4 + 0] = 0.f;
      dout[65618 + b * 4 + 1] = oa01;
      dout[65618 + b * 4 + 2] = oa10;
      dout[65618 + b * 4 + 3] = 0.f;
    }
  }
  __syncthreads();
  int f = fc * 64 + (t & 63);
  int ic = t >> 6;                         // 0..3 -> 16 i's each
  float o0s = 0.f, o1s = 0.f;
  for (int i = ic * 16; i < ic * 16 + 16; ++i) {
    o0s += outpart[(size_t)(b * 64 + i) * 1024 + f];
    o1s += outpart[(size_t)(b * 64 + i) * 1024 + 512 + f];
  }
  r0[ic * 64 + (t & 63)] = o0s;
  r1[ic * 64 + (t & 63)] = o1s;
  __syncthreads();
  if (ic == 0) {
    int fl = t & 63;
    float a0 = r0[fl] + r0[64 + fl] + r0[128 + fl] + r0[192 + fl];
    float a1 = r1[fl] + r1[64 + fl] + r1[128 + fl] + r1[192 + fl];
    uv[b * HID + f] = sc[1] * a1 + sc[0] * a0;   // u = oa10*o1 + oa01*o0
    uv[BB * HID + b * HID + f] = a0 + a1;        // v
  }
}

// ---------------------------------------------------------------------------
// Kernel G2: conv3 split-K partials. Grid 128 = kc(16) x fc(8).
// ---------------------------------------------------------------------------
__global__ __launch_bounds__(256) void conv3_part(
    const float* __restrict__ uv, const float* __restrict__ Wrel3,
    const float* __restrict__ Wroot3, float* __restrict__ xmacc) {
  __shared__ float us[8][32], vs[8][32];
  __shared__ float red[4][64][8];
  int blk = blockIdx.x;
  int fc = blk & 7, kc = blk >> 3;
  int t = threadIdx.x;
  {
    int b = t >> 5, k = t & 31;
    us[b][k] = uv[b * HID + kc * 32 + k];
    vs[b][k] = uv[BB * HID + b * HID + kc * 32 + k];
  }
  __syncthreads();
  int f = fc * 64 + (t & 63);
  int ks = t >> 6;                 // 0..3
  float acc[8] = {0, 0, 0, 0, 0, 0, 0, 0};
#pragma unroll
  for (int j = 0; j < 8; ++j) {
    int kl = ks * 8 + j;           // 0..31
    int k = kc * 32 + kl;
    float wr = Wrel3[k * HID + f];
    float wo = Wroot3[k * HID + f];
#pragma unroll
    for (int b = 0; b < 8; ++b)
      acc[b] += us[b][kl] * wr + vs[b][kl] * wo;
  }
#pragma unroll
  for (int b = 0; b < 8; ++b) red[ks][t & 63][b] = acc[b];
  __syncthreads();
  if (ks == 0) {
    int fl = t & 63;
#pragma unroll
    for (int b = 0; b < 8; ++b) {
      float v = red[0][fl][b] + red[1][fl][b] + red[2][fl][b] + red[3][fl][b];
      atomicAdd(&xmacc[b * HID + f], v);
    }
  }
}

// ---------------------------------------------------------------------------
// Kernel G3: lin1 split-K partials; xm = 0.5*xmacc + brel3 at staging.
// ---------------------------------------------------------------------------
__global__ __launch_bounds__(256) void lin1_part(
    const float* __restrict__ xmacc, const float* __restrict__ brel3,
    const float* __restrict__ Wlin1, float* __restrict__ h2acc) {
  __shared__ float xs[8][32];
  __shared__ float red[4][64][8];
  int blk = blockIdx.x;
  int fc = blk & 7, kc = blk >> 3;
  int t = threadIdx.x;
  {
    int b = t >> 5, k = t & 31;
    xs[b][k] = 0.5f * xmacc[b * HID + kc * 32 + k] + brel3[kc * 32 + k];
  }
  __syncthreads();
  int f = fc * 64 + (t & 63);
  int ks = t >> 6;
  float acc[8] = {0, 0, 0, 0, 0, 0, 0, 0};
#pragma unroll
  for (int j = 0; j < 8; ++j) {
    int kl = ks * 8 + j;
    int k = kc * 32 + kl;
    float w = Wlin1[k * HID + f];
#pragma unroll
    for (int b = 0; b < 8; ++b)
      acc[b] += xs[b][kl] * w;
  }
#pragma unroll
  for (int b = 0; b < 8; ++b) red[ks][t & 63][b] = acc[b];
  __syncthreads();
  if (ks == 0) {
    int fl = t & 63;
#pragma unroll
    for (int b = 0; b < 8; ++b) {
      float v = red[0][fl][b] + red[1][fl][b] + red[2][fl][b] + red[3][fl][b];
      atomicAdd(&h2acc[b * HID + f], v);
    }
  }
}

// ---------------------------------------------------------------------------
// Kernel G4: logits + log_softmax; h2 = relu(h2acc + blin1) at staging.
// Block 0 additionally sums the per-graph loss partials into dout[80,81].
// ---------------------------------------------------------------------------
__global__ __launch_bounds__(256) void head(
    const float* __restrict__ h2acc, const float* __restrict__ blin1,
    const float* __restrict__ Wlin2, const float* __restrict__ blin2,
    const float* __restrict__ lossp, float* __restrict__ dout) {
  __shared__ float hs[HID];
  __shared__ float lg[16];
  __shared__ float lse;
  int b = blockIdx.x, t = threadIdx.x;
  if (b == 0 && t == 255) {
    float l0 = 0.f, l1 = 0.f;
#pragma unroll
    for (int i = 0; i < BB; ++i) { l0 += lossp[i * 2]; l1 += lossp[i * 2 + 1]; }
    dout[80] = l0;
    dout[81] = l1;
  }
  for (int i = t; i < HID; i += 256)
    hs[i] = fmaxf(h2acc[b * HID + i] + blin1[i], 0.f);
  __syncthreads();
  int wave = t >> 6, lane = t & 63;
  for (int o = wave; o < OUTC; o += 4) {
    float acc = 0.f;
    for (int k = lane; k < HID; k += 64)
      acc += hs[k] * Wlin2[k * OUTC + o];
#pragma unroll
    for (int off = 32; off; off >>= 1) acc += __shfl_down(acc, off, 64);
    if (lane == 0) lg[o] = acc + blin2[o];
  }
  __syncthreads();
  if (t == 0) {
    float m = lg[0];
    for (int o = 1; o < OUTC; ++o) m = fmaxf(m, lg[o]);
    float se = 0.f;
    for (int o = 0; o < OUTC; ++o) se += expf(lg[o] - m);
    lse = m + logf(se);
  }
  __syncthreads();
  if (t < OUTC) dout[b * OUTC + t] = lg[t] - lse;
}

// ---------------------------------------------------------------------------
// Launcher
// ---------------------------------------------------------------------------
extern "C" void kernel_launch(void* const* d_in, const int* in_sizes, int n_in,
                              void* d_out, int out_size, void* d_ws, size_t ws_size,
                              hipStream_t stream) {
  const float* x      = (const float*)d_in[0];
  const int*   ei     = (const int*)d_in[1];
  const float* ew     = (const float*)d_in[3];
  const float* Wrel1  = (const float*)d_in[4];
  const float* brel1  = (const float*)d_in[5];
  const float* Wroot1 = (const float*)d_in[6];
  const float* Wpool  = (const float*)d_in[7];
  const float* bpool  = (const float*)d_in[8];
  const float* Wrel3  = (const float*)d_in[9];
  const float* brel3  = (const float*)d_in[10];
  const float* Wroot3 = (const float*)d_in[11];
  const float* Wlin1  = (const float*)d_in[12];
  const float* blin1  = (const float*)d_in[13];
  const float* Wlin2  = (const float*)d_in[14];
  const float* blin2  = (const float*)d_in[15];
  float* out = (float*)d_out;
  float* ws  = (float*)d_ws;

  // workspace layout (float units) — zero region is one contiguous block:
  //   [40960, 81992): oadj, ssacc, mden, deg, xmacc, h2acc
  float* oadj  = ws + 40960;                // [40960, 40992)
  float* ssacc = oadj + 32;                 // [40992, 41024)
  float* mden  = ssacc + 32;                // [41024, 41032)
  int*   deg   = (int*)(mden + 8);          // [41032, 73800)
  float* xmacc = ws + 73800;                // [73800, 77896)
  float* h2acc = xmacc + 4096;              // [77896, 81992)  zero-region end
  float* lossp = ws + 81992;                // [81992, 82008)  written each run
  ushort* Ab   = (ushort*)(ws + 106568);    // 32768x256 bf16  [106568, 4300872)
  ushort* Bb   = (ushort*)(ws + 4300872);   // 512x256 bf16    [4300872, 4366408)
  ushort* hbf  = (ushort*)(ws + 4366408);   // 32768x512 bf16  [4366408, 12755016)
  float* outpart = ws + 12763208;           // 512*1024        [12763208, 13287496)
  float* s     = ws + 16000000;             // 32768x2 fp32    [16000000, 16065536)
  // aliases (lifetimes by stream order):
  int2*  ell   = (int2*)(ws + 4366408);     // 16.8MB inside hbf region, dead pre-gemm
  float* uv    = (float*)deg;               // deg dead after gather_ell

  const int* src = ei;
  const int* dst = ei + BE;

  hipMemsetAsync(ws + 40960, 0, (size_t)41032 * sizeof(float), stream);

  front      <<<6656, 256, 0, stream>>>(src, dst, ew, x, Wrel1, Wroot1,
                                        deg, ell, Ab, Bb);
  gather_ell <<<BN / 4, 256, 0, stream>>>(deg, ell, Ab);
  gemm_pool  <<<512, 256, 0, stream>>>(Ab, Bb, brel1, Wpool, bpool, hbf,
                                       s, out + 82, outpart, ssacc);
  edge_pass2 <<<BB * 64, 256, 0, stream>>>(src, dst, ew, s, oadj, mden);
  finalize_a <<<64, 256, 0, stream>>>(outpart, oadj, ssacc, mden, uv, lossp, out);
  conv3_part <<<128, 256, 0, stream>>>(uv, Wrel3, Wroot3, xmacc);
  lin1_part  <<<128, 256, 0, stream>>>(xmacc, brel3, Wlin1, h2acc);
  head       <<<BB, 256, 0, stream>>>(h2acc, blin1, Wlin2, blin2, lossp, out);
}